// Round 5
// baseline (256.476 us; speedup 1.0000x reference)
//
#include <hip/hip_runtime.h>
#include <math.h>

// ---------------- problem constants ----------------
constexpr int B   = 16;
constexpr int H   = 512, W = 512;
constexpr int HW  = H * W;          // 262144
constexpr int P4  = 128;            // after 4x4 block sum
constexpr int P4N = P4 * P4;        // 16384
constexpr int P8N = 64 * 64;        // 4096
constexpr int NIMG = 2 * B;

// Sinkhorn K = exp(-10*d^2): taps beyond |d|=1 are below fp32 rounding of the
// center term -> 5-point separable stencil is fp32-exact.
constexpr float KW1 = 4.5399929762484854e-05f;  // exp(-10)
constexpr float KC2 = 4.1223072448771156e-09f;  // 2*exp(-20) (diag K*C weight)

// ---------------- workspace layout (float offsets) ----------------
constexpr size_t OFF_P4   = 0;                              // [32][128][128]
constexpr size_t OFF_P8   = OFF_P4  + (size_t)NIMG * P4N;   // [32][64][64]
constexpr size_t OFF_PART = OFF_P8  + (size_t)NIMG * P8N;   // [512] block partials

// DPP wave-wide shifts (VALU pipe, zero-fill at wave edges).
__device__ __forceinline__ float dpp_up(float x) {          // lane i <- i-1
    return __int_as_float(__builtin_amdgcn_update_dpp(
        0, __float_as_int(x), 0x138, 0xf, 0xf, true));
}
__device__ __forceinline__ float dpp_dn(float x) {          // lane i <- i+1
    return __int_as_float(__builtin_amdgcn_update_dpp(
        0, __float_as_int(x), 0x130, 0xf, 0xf, true));
}

// ---------------- fused 4x4 + 8x8 block sums + partials ----------------
__global__ void k_pre8(const float* __restrict__ pred, const float* __restrict__ gt,
                       float* __restrict__ ws, float* __restrict__ out, int out_size) {
    int tid = threadIdx.x, bx = blockIdx.x;
    if (bx == 0) {
        for (int i = tid; i < out_size; i += 256) out[i] = 0.f;
    }
    int gid = bx * 256 + tid;                 // [0, 32*4096)
    int img = gid >> 12;
    int rem = gid & (P8N - 1);
    int y = rem >> 6, x = rem & 63;
    const float* src = (img < B) ? (pred + (size_t)img * HW)
                                 : (gt + (size_t)(img - B) * HW);
    const float4* s4 = reinterpret_cast<const float4*>(src);
    int base = y * 8 * 128 + x * 2;
    float q00 = 0.f, q01 = 0.f, q10 = 0.f, q11 = 0.f;
#pragma unroll
    for (int r = 0; r < 8; r++) {
        float4 a0 = s4[base + r * 128];
        float4 a1 = s4[base + r * 128 + 1];
        float sa = a0.x + a0.y + a0.z + a0.w;
        float sb = a1.x + a1.y + a1.z + a1.w;
        if (r < 4) { q00 += sa; q01 += sb; } else { q10 += sa; q11 += sb; }
    }
    float2* p42 = reinterpret_cast<float2*>(ws + OFF_P4 + (size_t)img * P4N);
    p42[(2 * y) * 64 + x]     = make_float2(q00, q01);   // coalesced 512B/row
    p42[(2 * y + 1) * 64 + x] = make_float2(q10, q11);
    float s8 = q00 + q01 + q10 + q11;
    ws[OFF_P8 + gid] = s8;
    float part = s8;
#pragma unroll
    for (int o = 32; o > 0; o >>= 1) part += __shfl_down(part, o, 64);
    __shared__ float r4[4];
    int lane = tid & 63, wid = tid >> 6;
    if (lane == 0) r4[wid] = part;
    __syncthreads();
    if (tid == 0) ws[OFF_PART + bx] = r4[0] + r4[1] + r4[2] + r4[3];
}

// ---- one separable 49-tap Gaussian pass; conv result -> cvreg[32]/thread ----
// Returns the image's conv sum (broadcast to all threads). hbuf row-swizzled.
__device__ __forceinline__ float conv_pass(const float* __restrict__ src, float inv,
                                           const float* __restrict__ wlds,
                                           float* __restrict__ hbuf,
                                           float* __restrict__ rs,
                                           float* __restrict__ cvreg, int tid) {
    // ---- H phase: 2048 units = 128 rows x 16 segs (8 outputs each) ----
#pragma unroll
    for (int g = 0; g < 4; g++) {
        int unit = g * 512 + tid;
        int r = unit >> 4, seg = unit & 15, x0 = seg * 8;
        const float4* row4 = reinterpret_cast<const float4*>(src + (size_t)r * 128);
        float v[56];
#pragma unroll
        for (int j = 0; j < 14; j++) {
            int fx = (x0 - 24) / 4 + j;
            float4 t = (fx >= 0 && fx < 32) ? row4[fx] : make_float4(0.f, 0.f, 0.f, 0.f);
            v[4 * j] = t.x; v[4 * j + 1] = t.y; v[4 * j + 2] = t.z; v[4 * j + 3] = t.w;
        }
        float o8[8];
#pragma unroll
        for (int i = 0; i < 8; i++) o8[i] = 0.f;
#pragma unroll
        for (int k = 0; k < 49; k++) {
            float wk = wlds[k];
#pragma unroll
            for (int i = 0; i < 8; i++) o8[i] = fmaf(wk, v[i + k], o8[i]);
        }
        int sw = r & 31;
#pragma unroll
        for (int i = 0; i < 8; i++)
            hbuf[r * 128 + ((x0 + i) ^ sw)] = o8[i] * inv;
    }
    __syncthreads();

    // ---- V phase: 2048 units = 128 cols x 16 row-segs -> registers ----
    float part = 0.f;
#pragma unroll
    for (int g = 0; g < 4; g++) {
        int unit = g * 512 + tid;
        int c = unit & 127, rseg = unit >> 7, r0 = rseg * 8;
        float v[56];
#pragma unroll
        for (int j = 0; j < 56; j++) {
            int rr = r0 - 24 + j;
            v[j] = (rr >= 0 && rr < 128) ? hbuf[rr * 128 + (c ^ (rr & 31))] : 0.f;
        }
        float o8[8];
#pragma unroll
        for (int i = 0; i < 8; i++) o8[i] = 0.f;
#pragma unroll
        for (int k = 0; k < 49; k++) {
            float wk = wlds[k];
#pragma unroll
            for (int i = 0; i < 8; i++) o8[i] = fmaf(wk, v[i + k], o8[i]);
        }
#pragma unroll
        for (int i = 0; i < 8; i++) {
            float s = o8[i] * inv;
            cvreg[g * 8 + i] = s;
            part += s;
        }
    }
#pragma unroll
    for (int o = 32; o > 0; o >>= 1) part += __shfl_down(part, o, 64);
    int lane = tid & 63, w = tid >> 6;
    if (lane == 0) rs[w] = part;
    __syncthreads();        // also separates V-reads of hbuf from next H-writes
    float tot = 0.f;
#pragma unroll
    for (int i = 0; i < 8; i++) tot += rs[i];
    return tot;
}

// ---------------- mega kernel: blocks 0..15 conv-pair+KL/L2, 16..31 OT ------
__global__ void __launch_bounds__(512, 2) k_mega(float* __restrict__ ws,
                                                 const int* __restrict__ gtc,
                                                 const int* __restrict__ carea,
                                                 float* __restrict__ out) {
    __shared__ float hbuf[P4N];               // conv: h-pass tile | ot: halos
    __shared__ float wlds[49];
    __shared__ float rs[8];
    int tid = threadIdx.x;
    int lane = tid & 63, w = tid >> 6;

    if (blockIdx.x < 16) {
        // ============ conv-pair role: Gaussian(pred b) + Gaussian(gt b) =====
        int b = blockIdx.x;
        if (tid < 49) {
            float xx = (float)(tid - 24);
            wlds[tid] = expf(-xx * xx * (1.f / 128.f));
        }
        __syncthreads();
        float norm = 0.f;
#pragma unroll
        for (int k = 0; k < 49; k++) norm += wlds[k];
        float inv = 1.f / norm;

        float cv_p[32], cv_g[32];
        float sum_p = conv_pass(ws + OFF_P4 + (size_t)b * P4N, inv, wlds, hbuf, rs,
                                cv_p, tid);
        float sum_g = conv_pass(ws + OFF_P4 + (size_t)(B + b) * P4N, inv, wlds, hbuf,
                                rs, cv_g, tid);

        // ---- KL + L2, all in registers ----
        float isp = 1.f / fmaxf(sum_p, 1e-8f);
        float isg = 1.f / fmaxf(sum_g, 1e-8f);
        float part = 0.f;
#pragma unroll
        for (int j = 0; j < 32; j++) {
            float pn = cv_p[j] * isp, gn = cv_g[j] * isg;
            float d = pn - gn;
            part += gn * __logf((gn + 1e-8f) / (pn + 1e-8f)) + d * d;
        }
#pragma unroll
        for (int o = 32; o > 0; o >>= 1) part += __shfl_down(part, o, 64);
        if (lane == 0) rs[w] = part;
        __syncthreads();
        if (tid == 0) {
            float s = 0.f;
#pragma unroll
            for (int i = 0; i < 8; i++) s += rs[i];
            atomicAdd(out, (0.5f / 16.f) * s);
        }
    } else {
        // ================= OT role: Sinkhorn, 1 batch/block =================
        int b = blockIdx.x - 16;
        int r0 = w << 3;
        float* H0 = hbuf;                      // [4][8][64]
        float* H1 = hbuf + 2048;

        const float* PART = ws + OFF_PART;
        float rawA = 0.f, rawB = 0.f;
#pragma unroll
        for (int j = 0; j < 16; j++) {
            rawA += PART[b * 16 + j];
            rawB += PART[(B + b) * 16 + j];
        }
        float asum = fmaxf(rawA, 1e-8f), bsum = fmaxf(rawB, 1e-8f);
        float ai = 1.f / asum, bi = 1.f / bsum;
        const float* ap = ws + OFF_P8 + (size_t)b * P8N;
        const float* bp = ws + OFF_P8 + (size_t)(B + b) * P8N;

        float ar[8], br10[10], cur[8], vr[10];
#pragma unroll
        for (int k = 0; k < 8; k++) {
            ar[k] = ap[(r0 + k) * 64 + lane] * ai;   // coalesced
            cur[k] = 1.f;
        }
#pragma unroll
        for (int i = 0; i < 10; i++) {
            int rr = r0 - 1 + i;
            br10[i] = (rr >= 0 && rr < 64) ? bp[rr * 64 + lane] * bi : 0.f;
        }

        for (int it = 0; it < 50; it++) {
            float* Hp = (it & 1) ? H1 : H0;
            Hp[(0 * 8 + w) * 64 + lane] = cur[0];
            Hp[(1 * 8 + w) * 64 + lane] = cur[1];
            Hp[(2 * 8 + w) * 64 + lane] = cur[6];
            Hp[(3 * 8 + w) * 64 + lane] = cur[7];
            __syncthreads();
            float uext[12];
            uext[0]  = w ? Hp[(2 * 8 + w - 1) * 64 + lane] : 0.f;   // row r0-2
            uext[1]  = w ? Hp[(3 * 8 + w - 1) * 64 + lane] : 0.f;   // row r0-1
#pragma unroll
            for (int k = 0; k < 8; k++) uext[2 + k] = cur[k];
            uext[10] = (w < 7) ? Hp[(0 * 8 + w + 1) * 64 + lane] : 0.f;
            uext[11] = (w < 7) ? Hp[(1 * 8 + w + 1) * 64 + lane] : 0.f;

            // v = b / (K u + eps) on rows r0-1..r0+8 (2 redundant)
            float tr[10];
#pragma unroll
            for (int i = 0; i < 10; i++)
                tr[i] = fmaf(KW1, uext[i] + uext[i + 2], uext[i + 1]);
#pragma unroll
            for (int i = 0; i < 10; i++) {
                float s = fmaf(KW1, dpp_up(tr[i]) + dpp_dn(tr[i]), tr[i]) + 1e-8f;
                vr[i] = br10[i] * __builtin_amdgcn_rcpf(s);
            }
            // u = a / (K v + eps) on rows r0..r0+7
            float t2[8];
#pragma unroll
            for (int k = 0; k < 8; k++)
                t2[k] = fmaf(KW1, vr[k] + vr[k + 2], vr[k + 1]);
#pragma unroll
            for (int k = 0; k < 8; k++) {
                float s = fmaf(KW1, dpp_up(t2[k]) + dpp_dn(t2[k]), t2[k]) + 1e-8f;
                cur[k] = ar[k] * __builtin_amdgcn_rcpf(s);
            }
        }

        // ---- cost = u . (K*C) v : 3x3 stencil; vr has the +-1 row halo ----
        float dL[10], dR[10];
#pragma unroll
        for (int i = 0; i < 10; i++) { dL[i] = dpp_up(vr[i]); dR[i] = dpp_dn(vr[i]); }
        float part = 0.f;
#pragma unroll
        for (int k = 0; k < 8; k++) {
            float s = KW1 * (vr[k] + vr[k + 2] + dL[k + 1] + dR[k + 1])
                    + KC2 * (dL[k] + dR[k] + dL[k + 2] + dR[k + 2]);
            part = fmaf(cur[k], s, part);
        }
#pragma unroll
        for (int o = 32; o > 0; o >>= 1) part += __shfl_down(part, o, 64);
        if (lane == 0) rs[w] = part;
        __syncthreads();
        if (tid == 0) {
            float c = 0.f;
#pragma unroll
            for (int i = 0; i < 8; i++) c += rs[i];
            float ot = (asum > 0.5f && bsum > 0.5f) ? c : 0.f;
            int cv = carea[0];
            float ca = (cv >= 1 && cv < 16777216) ? (float)cv : __int_as_float(cv);
            float pc = fmaxf(rawA / ca, 0.f);
            float d = fabsf(pc - (float)gtc[b]);
            float cl = (d < 10.f) ? (0.05f * d * d) : (d - 5.f);
            atomicAdd(out, 0.3f * ot * (1.f / 16.f) + 3.f * cl * (1.f / 16.f));
        }
    }
}

// ---------------- launcher ----------------
extern "C" void kernel_launch(void* const* d_in, const int* in_sizes, int n_in,
                              void* d_out, int out_size, void* d_ws, size_t ws_size,
                              hipStream_t stream) {
    const float* pred = (const float*)d_in[0];
    const float* gt   = (const float*)d_in[1];
    const int* gtc    = (const int*)d_in[2];
    const int* ca     = (const int*)d_in[3];
    float* out = (float*)d_out;
    float* ws  = (float*)d_ws;

    k_pre8<<<512, 256, 0, stream>>>(pred, gt, ws, out, out_size);
    k_mega<<<32, 512, 0, stream>>>(ws, gtc, ca, out);
}